// Round 5
// baseline (313.359 us; speedup 1.0000x reference)
//
#include <hip/hip_runtime.h>

#define BN_EPS 1e-3f

typedef __attribute__((ext_vector_type(8))) short bf16x8;
typedef __attribute__((ext_vector_type(4))) float f32x4;

__device__ __forceinline__ short f2bf(float f) {
    union { float f; unsigned u; } a; a.f = f;
    unsigned r = a.u + 0x7fffu + ((a.u >> 16) & 1u);
    return (short)(r >> 16);
}
__device__ __forceinline__ float bf2f(short s) {
    union { unsigned u; float f; } a;
    a.u = ((unsigned)(unsigned short)s) << 16;
    return a.f;
}

// ---------------- K1: GIN aggregation as binary-MFMA GEMM ----------------
// h0[b,i,f] = (1+eps)*x[b,i,f] + sum_j a[b,i,j]*x[b,j,f]
// a is binary -> bf16-exact A operand; x split hi/lo (2-term).
// 256 blocks = 32 batches x 8 row-tiles (BM=128); 8 waves (4 rowgrp x 2 colgrp).
__global__ __launch_bounds__(512, 2) void agg_mfma(
    const float* __restrict__ x, const float* __restrict__ a,
    const float* __restrict__ epsp, float* __restrict__ h0) {
    __shared__ __align__(16) ushort Aab[4][128][8];   // 8 KB  A(row, k=kg*8+e)
    __shared__ __align__(16) ushort Xh[4][128][8];    // 8 KB  x-hi(k, col=f)
    __shared__ __align__(16) ushort Xl[4][128][8];    // 8 KB  x-lo

    const int tid  = threadIdx.x;
    const int lane = tid & 63;
    const int wid  = tid >> 6;
    const int wr   = wid >> 1;       // row group: 32 rows
    const int wn   = wid & 1;        // col group: 64 f
    const int lr   = lane & 15;
    const int kg   = lane >> 4;
    const int b    = blockIdx.x >> 3;
    const int row0 = (blockIdx.x & 7) * 128;

    const float* ab = a + ((size_t)b * 1024 + row0) * 1024;   // [128][1024]
    const float* xb = x + (size_t)b * 1024 * 128;             // [1024][128]

    // staging assignments
    const int ai  = tid >> 2;        // 0..127 (a row)
    const int akq = tid & 3;         // k-quad (8 elems)
    const int xkg = tid >> 7;        // 0..3
    const int xf  = tid & 127;       // f col

    f32x4 acc[2][4] = {};

    for (int kc = 0; kc < 32; ++kc) {
        const int k0 = kc * 32;
        // issue global loads before the barrier (overlap prior MFMA)
        f32x4 a0 = *reinterpret_cast<const f32x4*>(ab + (size_t)ai * 1024 + k0 + akq * 8);
        f32x4 a1 = *reinterpret_cast<const f32x4*>(ab + (size_t)ai * 1024 + k0 + akq * 8 + 4);
        float xv[8];
        #pragma unroll
        for (int e = 0; e < 8; ++e)
            xv[e] = xb[(size_t)(k0 + xkg * 8 + e) * 128 + xf];   // coalesced per-e
        __syncthreads();                  // prior chunk's frag reads done
        {
            float av[8] = {a0.x, a0.y, a0.z, a0.w, a1.x, a1.y, a1.z, a1.w};
            bf16x8 h8;
            #pragma unroll
            for (int e = 0; e < 8; ++e) h8[e] = f2bf(av[e]);     // exact: av in {0,1}
            *reinterpret_cast<bf16x8*>(&Aab[akq][ai][0]) = h8;
            bf16x8 xh8, xl8;
            #pragma unroll
            for (int e = 0; e < 8; ++e) {
                const short hh = f2bf(xv[e]);
                xh8[e] = hh; xl8[e] = f2bf(xv[e] - bf2f(hh));
            }
            *reinterpret_cast<bf16x8*>(&Xh[xkg][xf][0]) = xh8;
            *reinterpret_cast<bf16x8*>(&Xl[xkg][xf][0]) = xl8;
        }
        __syncthreads();

        bf16x8 af0 = *reinterpret_cast<bf16x8*>(&Aab[kg][wr * 32 + lr][0]);
        bf16x8 af1 = *reinterpret_cast<bf16x8*>(&Aab[kg][wr * 32 + 16 + lr][0]);
        #pragma unroll
        for (int ni = 0; ni < 4; ++ni) {
            bf16x8 bh = *reinterpret_cast<bf16x8*>(&Xh[kg][wn * 64 + ni * 16 + lr][0]);
            bf16x8 bl = *reinterpret_cast<bf16x8*>(&Xl[kg][wn * 64 + ni * 16 + lr][0]);
            acc[0][ni] = __builtin_amdgcn_mfma_f32_16x16x32_bf16(af0, bh, acc[0][ni], 0, 0, 0);
            acc[0][ni] = __builtin_amdgcn_mfma_f32_16x16x32_bf16(af0, bl, acc[0][ni], 0, 0, 0);
            acc[1][ni] = __builtin_amdgcn_mfma_f32_16x16x32_bf16(af1, bh, acc[1][ni], 0, 0, 0);
            acc[1][ni] = __builtin_amdgcn_mfma_f32_16x16x32_bf16(af1, bl, acc[1][ni], 0, 0, 0);
        }
    }

    // epilogue: h0 = (1+eps)*x + agg  (verified C layout)
    const float ep1 = 1.0f + epsp[0];
    #pragma unroll
    for (int ni = 0; ni < 4; ++ni) {
        const int col = wn * 64 + ni * 16 + lr;
        #pragma unroll
        for (int mi = 0; mi < 2; ++mi) {
            const int rbase = row0 + wr * 32 + mi * 16 + (lane >> 4) * 4;
            #pragma unroll
            for (int r = 0; r < 4; ++r) {
                const size_t xoff = (size_t)(rbase + r) * 128 + col;
                h0[(size_t)b * 131072 + xoff] = fmaf(ep1, xb[xoff], acc[mi][ni][r]);
            }
        }
    }
}

// ---------------- K2: W pre-split into LDS chunk images (verified) --------
// Layout per 32-k chunk (16384 ushorts = 32KB): hi[4 kg][256 c][8 e] then lo.
// Layer bases (ushorts): L1=0 (4 chunks), L2=65536 (8), L3=196608 (8).
__global__ __launch_bounds__(256) void prep_w(
    const float* __restrict__ w1, const float* __restrict__ w2,
    const float* __restrict__ w3, ushort* __restrict__ Wp) {
    const int k = blockIdx.x;      // 0..639 global k row
    const int c = threadIdx.x;     // 0..255
    const float* src; int kl, base;
    if (k < 128)      { src = w1; kl = k;       base = 0; }
    else if (k < 384) { src = w2; kl = k - 128; base = 65536; }
    else              { src = w3; kl = k - 384; base = 196608; }
    const float val = src[(size_t)kl * 256 + c];
    const short hi = f2bf(val);
    const short lo = f2bf(val - bf2f(hi));
    const int off = base + (kl >> 5) * 16384 + ((((kl >> 3) & 3) * 256 + c) * 8) + (kl & 7);
    Wp[off]        = (ushort)hi;
    Wp[off + 8192] = (ushort)lo;
}

// ---------------- K3: fused 3-layer MLP + max-pool (verified) -------------
__global__ __launch_bounds__(512, 2) void fused_mlp(
    const float* __restrict__ h0, const ushort* __restrict__ Wp,
    const float* __restrict__ b1, const float* __restrict__ g1,
    const float* __restrict__ be1, const float* __restrict__ m1,
    const float* __restrict__ v1,
    const float* __restrict__ b2, const float* __restrict__ g2,
    const float* __restrict__ be2, const float* __restrict__ m2,
    const float* __restrict__ v2,
    const float* __restrict__ b3, const float* __restrict__ g3,
    const float* __restrict__ be3, const float* __restrict__ m3,
    const float* __restrict__ v3,
    float* __restrict__ pool) {
    __shared__ __align__(16) ushort Wb[2][4][256][8];    // 32KB: [hi/lo][kg][col][e]
    __shared__ __align__(16) ushort Ab[2][4][4][32][8];  // 16KB: [hi/lo][wr][kg][row][e]

    const int tid  = threadIdx.x;
    const int lane = tid & 63;
    const int wid  = tid >> 6;
    const int wr   = wid >> 1;     // row group (32 rows each)
    const int wn   = wid & 1;      // col group (128 cols each)
    const int lr   = lane & 15;
    const int kg   = lane >> 4;
    const int row0 = blockIdx.x * 128;

    f32x4 acc1[2][8] = {};
    f32x4 acc2[2][8] = {};

    // ---- Layer 1: A from global h0 (fp32), K=128, 4 chunks ----
    const int arow = tid >> 2;          // 0..127
    const int akq  = tid & 3;           // k-quad (8 floats)
    const float* aptr = h0 + (size_t)(row0 + arow) * 128 + akq * 8;

    #pragma unroll
    for (int kc = 0; kc < 4; ++kc) {
        f32x4 a0 = *reinterpret_cast<const f32x4*>(aptr + kc * 32);
        f32x4 a1 = *reinterpret_cast<const f32x4*>(aptr + kc * 32 + 4);
        const f32x4* wsrc = reinterpret_cast<const f32x4*>(Wp + kc * 16384);
        f32x4 wv0 = wsrc[tid], wv1 = wsrc[512 + tid];
        f32x4 wv2 = wsrc[1024 + tid], wv3 = wsrc[1536 + tid];
        __syncthreads();                 // prior chunk's frag reads done
        {
            float av[8] = {a0.x, a0.y, a0.z, a0.w, a1.x, a1.y, a1.z, a1.w};
            bf16x8 hi, lo;
            #pragma unroll
            for (int e = 0; e < 8; ++e) {
                const short h = f2bf(av[e]);
                hi[e] = h; lo[e] = f2bf(av[e] - bf2f(h));
            }
            *reinterpret_cast<bf16x8*>(&Ab[0][arow >> 5][akq][arow & 31][0]) = hi;
            *reinterpret_cast<bf16x8*>(&Ab[1][arow >> 5][akq][arow & 31][0]) = lo;
        }
        f32x4* wdst = reinterpret_cast<f32x4*>(Wb);
        wdst[tid] = wv0; wdst[512 + tid] = wv1;
        wdst[1024 + tid] = wv2; wdst[1536 + tid] = wv3;
        __syncthreads();

        bf16x8 ah0 = *reinterpret_cast<bf16x8*>(&Ab[0][wr][kg][lr][0]);
        bf16x8 al0 = *reinterpret_cast<bf16x8*>(&Ab[1][wr][kg][lr][0]);
        bf16x8 ah1 = *reinterpret_cast<bf16x8*>(&Ab[0][wr][kg][16 + lr][0]);
        bf16x8 al1 = *reinterpret_cast<bf16x8*>(&Ab[1][wr][kg][16 + lr][0]);
        #pragma unroll
        for (int ni = 0; ni < 8; ++ni) {
            bf16x8 bh = *reinterpret_cast<bf16x8*>(&Wb[0][kg][wn * 128 + ni * 16 + lr][0]);
            bf16x8 bl = *reinterpret_cast<bf16x8*>(&Wb[1][kg][wn * 128 + ni * 16 + lr][0]);
            acc1[0][ni] = __builtin_amdgcn_mfma_f32_16x16x32_bf16(ah0, bh, acc1[0][ni], 0, 0, 0);
            acc1[0][ni] = __builtin_amdgcn_mfma_f32_16x16x32_bf16(ah0, bl, acc1[0][ni], 0, 0, 0);
            acc1[0][ni] = __builtin_amdgcn_mfma_f32_16x16x32_bf16(al0, bh, acc1[0][ni], 0, 0, 0);
            acc1[1][ni] = __builtin_amdgcn_mfma_f32_16x16x32_bf16(ah1, bh, acc1[1][ni], 0, 0, 0);
            acc1[1][ni] = __builtin_amdgcn_mfma_f32_16x16x32_bf16(ah1, bl, acc1[1][ni], 0, 0, 0);
            acc1[1][ni] = __builtin_amdgcn_mfma_f32_16x16x32_bf16(al1, bh, acc1[1][ni], 0, 0, 0);
        }
    }

    // epilogue 1: bias+BN+relu in place
    #pragma unroll
    for (int ni = 0; ni < 8; ++ni) {
        const int c = wn * 128 + ni * 16 + lr;
        const float s  = g1[c] * rsqrtf(v1[c] + BN_EPS);
        const float tt = be1[c] - m1[c] * s;
        const float bb = b1[c];
        #pragma unroll
        for (int mi = 0; mi < 2; ++mi)
            #pragma unroll
            for (int r = 0; r < 4; ++r)
                acc1[mi][ni][r] = fmaxf(fmaf(acc1[mi][ni][r] + bb, s, tt), 0.f);
    }

    // ---- Layer 2: A from acc1 (regs), K=256, 8 chunks ----
    #pragma unroll
    for (int kc = 0; kc < 8; ++kc) {
        const f32x4* wsrc = reinterpret_cast<const f32x4*>(Wp + 65536 + kc * 16384);
        f32x4 wv0 = wsrc[tid], wv1 = wsrc[512 + tid];
        f32x4 wv2 = wsrc[1024 + tid], wv3 = wsrc[1536 + tid];
        __syncthreads();
        if (wn == (kc >> 2)) {           // this wave's cols cover chunk kc
            #pragma unroll
            for (int j = 0; j < 2; ++j) {
                const int ni  = (kc & 3) * 2 + j;
                const int kgw = j * 2 + (lr >> 3);
                const int e   = lr & 7;
                #pragma unroll
                for (int mi = 0; mi < 2; ++mi)
                    #pragma unroll
                    for (int r = 0; r < 4; ++r) {
                        const float val = acc1[mi][ni][r];
                        const short h = f2bf(val);
                        Ab[0][wr][kgw][mi * 16 + kg * 4 + r][e] = (ushort)h;
                        Ab[1][wr][kgw][mi * 16 + kg * 4 + r][e] = (ushort)f2bf(val - bf2f(h));
                    }
            }
        }
        f32x4* wdst = reinterpret_cast<f32x4*>(Wb);
        wdst[tid] = wv0; wdst[512 + tid] = wv1;
        wdst[1024 + tid] = wv2; wdst[1536 + tid] = wv3;
        __syncthreads();

        bf16x8 ah0 = *reinterpret_cast<bf16x8*>(&Ab[0][wr][kg][lr][0]);
        bf16x8 al0 = *reinterpret_cast<bf16x8*>(&Ab[1][wr][kg][lr][0]);
        bf16x8 ah1 = *reinterpret_cast<bf16x8*>(&Ab[0][wr][kg][16 + lr][0]);
        bf16x8 al1 = *reinterpret_cast<bf16x8*>(&Ab[1][wr][kg][16 + lr][0]);
        #pragma unroll
        for (int ni = 0; ni < 8; ++ni) {
            bf16x8 bh = *reinterpret_cast<bf16x8*>(&Wb[0][kg][wn * 128 + ni * 16 + lr][0]);
            bf16x8 bl = *reinterpret_cast<bf16x8*>(&Wb[1][kg][wn * 128 + ni * 16 + lr][0]);
            acc2[0][ni] = __builtin_amdgcn_mfma_f32_16x16x32_bf16(ah0, bh, acc2[0][ni], 0, 0, 0);
            acc2[0][ni] = __builtin_amdgcn_mfma_f32_16x16x32_bf16(ah0, bl, acc2[0][ni], 0, 0, 0);
            acc2[0][ni] = __builtin_amdgcn_mfma_f32_16x16x32_bf16(al0, bh, acc2[0][ni], 0, 0, 0);
            acc2[1][ni] = __builtin_amdgcn_mfma_f32_16x16x32_bf16(ah1, bh, acc2[1][ni], 0, 0, 0);
            acc2[1][ni] = __builtin_amdgcn_mfma_f32_16x16x32_bf16(ah1, bl, acc2[1][ni], 0, 0, 0);
            acc2[1][ni] = __builtin_amdgcn_mfma_f32_16x16x32_bf16(al1, bh, acc2[1][ni], 0, 0, 0);
        }
    }

    // epilogue 2
    #pragma unroll
    for (int ni = 0; ni < 8; ++ni) {
        const int c = wn * 128 + ni * 16 + lr;
        const float s  = g2[c] * rsqrtf(v2[c] + BN_EPS);
        const float tt = be2[c] - m2[c] * s;
        const float bb = b2[c];
        #pragma unroll
        for (int mi = 0; mi < 2; ++mi)
            #pragma unroll
            for (int r = 0; r < 4; ++r)
                acc2[mi][ni][r] = fmaxf(fmaf(acc2[mi][ni][r] + bb, s, tt), 0.f);
    }

    // ---- Layer 3: A from acc2, accumulate into re-zeroed acc1 ----
    #pragma unroll
    for (int mi = 0; mi < 2; ++mi)
        #pragma unroll
        for (int ni = 0; ni < 8; ++ni)
            #pragma unroll
            for (int r = 0; r < 4; ++r)
                acc1[mi][ni][r] = 0.f;

    #pragma unroll
    for (int kc = 0; kc < 8; ++kc) {
        const f32x4* wsrc = reinterpret_cast<const f32x4*>(Wp + 196608 + kc * 16384);
        f32x4 wv0 = wsrc[tid], wv1 = wsrc[512 + tid];
        f32x4 wv2 = wsrc[1024 + tid], wv3 = wsrc[1536 + tid];
        __syncthreads();
        if (wn == (kc >> 2)) {
            #pragma unroll
            for (int j = 0; j < 2; ++j) {
                const int ni  = (kc & 3) * 2 + j;
                const int kgw = j * 2 + (lr >> 3);
                const int e   = lr & 7;
                #pragma unroll
                for (int mi = 0; mi < 2; ++mi)
                    #pragma unroll
                    for (int r = 0; r < 4; ++r) {
                        const float val = acc2[mi][ni][r];
                        const short h = f2bf(val);
                        Ab[0][wr][kgw][mi * 16 + kg * 4 + r][e] = (ushort)h;
                        Ab[1][wr][kgw][mi * 16 + kg * 4 + r][e] = (ushort)f2bf(val - bf2f(h));
                    }
            }
        }
        f32x4* wdst = reinterpret_cast<f32x4*>(Wb);
        wdst[tid] = wv0; wdst[512 + tid] = wv1;
        wdst[1024 + tid] = wv2; wdst[1536 + tid] = wv3;
        __syncthreads();

        bf16x8 ah0 = *reinterpret_cast<bf16x8*>(&Ab[0][wr][kg][lr][0]);
        bf16x8 al0 = *reinterpret_cast<bf16x8*>(&Ab[1][wr][kg][lr][0]);
        bf16x8 ah1 = *reinterpret_cast<bf16x8*>(&Ab[0][wr][kg][16 + lr][0]);
        bf16x8 al1 = *reinterpret_cast<bf16x8*>(&Ab[1][wr][kg][16 + lr][0]);
        #pragma unroll
        for (int ni = 0; ni < 8; ++ni) {
            bf16x8 bh = *reinterpret_cast<bf16x8*>(&Wb[0][kg][wn * 128 + ni * 16 + lr][0]);
            bf16x8 bl = *reinterpret_cast<bf16x8*>(&Wb[1][kg][wn * 128 + ni * 16 + lr][0]);
            acc1[0][ni] = __builtin_amdgcn_mfma_f32_16x16x32_bf16(ah0, bh, acc1[0][ni], 0, 0, 0);
            acc1[0][ni] = __builtin_amdgcn_mfma_f32_16x16x32_bf16(ah0, bl, acc1[0][ni], 0, 0, 0);
            acc1[0][ni] = __builtin_amdgcn_mfma_f32_16x16x32_bf16(al0, bh, acc1[0][ni], 0, 0, 0);
            acc1[1][ni] = __builtin_amdgcn_mfma_f32_16x16x32_bf16(ah1, bh, acc1[1][ni], 0, 0, 0);
            acc1[1][ni] = __builtin_amdgcn_mfma_f32_16x16x32_bf16(ah1, bl, acc1[1][ni], 0, 0, 0);
            acc1[1][ni] = __builtin_amdgcn_mfma_f32_16x16x32_bf16(al1, bh, acc1[1][ni], 0, 0, 0);
        }
    }

    // epilogue 3: bias+BN+relu -> wave max over 32 rows -> atomicMax pool
    const int b = blockIdx.x >> 3;
    #pragma unroll
    for (int ni = 0; ni < 8; ++ni) {
        const int c = wn * 128 + ni * 16 + lr;
        const float s  = g3[c] * rsqrtf(v3[c] + BN_EPS);
        const float tt = be3[c] - m3[c] * s;
        const float bb = b3[c];
        float mx = 0.0f;                 // relu floor
        #pragma unroll
        for (int mi = 0; mi < 2; ++mi)
            #pragma unroll
            for (int r = 0; r < 4; ++r)
                mx = fmaxf(mx, fmaf(acc1[mi][ni][r] + bb, s, tt));
        mx = fmaxf(mx, __shfl_xor(mx, 16));
        mx = fmaxf(mx, __shfl_xor(mx, 32));
        if (lane < 16)
            atomicMax((int*)&pool[b * 256 + c], __float_as_int(mx));
    }
}

// ---------------- K4: pool init (relu floor = 0) ----------------
__global__ __launch_bounds__(256) void pool_init(float* __restrict__ pool) {
    pool[blockIdx.x * 256 + threadIdx.x] = 0.0f;
}

// ---------------- K5: head Dense(3), wave-parallel ----------------
__global__ __launch_bounds__(256) void head_kernel(const float* __restrict__ pool,
                                                   const float* __restrict__ wd,
                                                   const float* __restrict__ bd,
                                                   float* __restrict__ out) {
    const int b = blockIdx.x;
    const int t = threadIdx.x;
    const int w = t >> 6;
    const int lane = t & 63;
    if (w < 3) {
        float s = 0.f;
        #pragma unroll
        for (int k = 0; k < 256; k += 64)
            s += pool[b * 256 + k + lane] * wd[(k + lane) * 3 + w];
        #pragma unroll
        for (int off = 32; off; off >>= 1) s += __shfl_down(s, off);
        if (lane == 0) out[b * 3 + w] = s + bd[w];
    }
}

extern "C" void kernel_launch(void* const* d_in, const int* in_sizes, int n_in,
                              void* d_out, int out_size, void* d_ws, size_t ws_size,
                              hipStream_t stream) {
    const float* x   = (const float*)d_in[0];
    const float* a   = (const float*)d_in[1];
    const float* eps = (const float*)d_in[2];
    const float* w1  = (const float*)d_in[3];
    const float* b1  = (const float*)d_in[4];
    const float* g1  = (const float*)d_in[5];
    const float* be1 = (const float*)d_in[6];
    const float* m1  = (const float*)d_in[7];
    const float* v1  = (const float*)d_in[8];
    const float* w2  = (const float*)d_in[9];
    const float* b2  = (const float*)d_in[10];
    const float* g2  = (const float*)d_in[11];
    const float* be2 = (const float*)d_in[12];
    const float* m2  = (const float*)d_in[13];
    const float* v2  = (const float*)d_in[14];
    const float* w3  = (const float*)d_in[15];
    const float* b3  = (const float*)d_in[16];
    const float* g3  = (const float*)d_in[17];
    const float* be3 = (const float*)d_in[18];
    const float* m3  = (const float*)d_in[19];
    const float* v3  = (const float*)d_in[20];
    const float* wd  = (const float*)d_in[21];
    const float* bd  = (const float*)d_in[22];
    float* out = (float*)d_out;

    // Workspace: h0 @0 (16MB), Wp @16MB (640KB), pool @17MB (32KB)
    char* ws = (char*)d_ws;
    float*  h0   = (float*)(ws);
    ushort* Wp   = (ushort*)(ws + (16u << 20));
    float*  pool = (float*)(ws + (17u << 20));

    pool_init<<<32, 256, 0, stream>>>(pool);
    prep_w<<<640, 256, 0, stream>>>(w1, w2, w3, Wp);
    agg_mfma<<<256, 512, 0, stream>>>(x, a, eps, h0);
    fused_mlp<<<256, 512, 0, stream>>>(h0, Wp,
        b1, g1, be1, m1, v1,
        b2, g2, be2, m2, v2,
        b3, g3, be3, m3, v3, pool);
    head_kernel<<<32, 256, 0, stream>>>(pool, wd, bd, out);
}